// Round 5
// baseline (348.902 us; speedup 1.0000x reference)
//
#include <hip/hip_runtime.h>

// Problem constants (match reference)
#define BATCHN 32
#define NCELL  4096
#define BN     (BATCHN * NCELL)

// Round 5: test the launch-overhead theory. R1-R4 (four different kernel
// structures: barriers/no barriers, 1 or 2 blocks/CU, batched stores) all
// landed at ~235-248 us =~ 23.5 us per dispatch, while the in-kernel
// critical path accounts for only ~5-8 us per 60-step dispatch. Remaining
// suspect: ~15-18 us of inter-dispatch overhead (AQL barrier + cross-XCD
// L2 writeback/invalidate so launch k+1 sees launch k's 31 MB of writes).
// Single-variable change: CPL 4->8, HALO 64->128, KSTEP 60->120
// => 5 launches instead of 10, identical math.
constexpr int CPL    = 8;                  // cells per lane
constexpr int CELLS  = 64 * CPL;           // 512 = OWN + 2*HALO
constexpr int HALO   = 128;
constexpr int OWN    = CELLS - 2 * HALO;   // 256
constexpr int KSTEP  = 120;                // steps per launch (<= HALO - 8)
constexpr int CHUNKS = NCELL / OWN;        // 16

// f(u) and |f'(u)| exactly as the reference's f_real + jvp derivative.
__device__ __forceinline__ void f_and_a(float u, float& f, float& a) {
    const float C56 = 0.8333333333333333f;  // 10/12 rounded to f32
    float u2 = u * u;
    float u4 = u2 * u2;
    float g  = 0.75f - 2.0f * u + 1.5f * u2 - 0.25f * u4;
    f = 0.5f * u * (3.0f - u2) + C56 * (u2 * g);
    float gp = -2.0f + 3.0f * u - u2 * u;
    float df = (1.5f - 1.5f * u2) + C56 * (2.0f * u * g + u2 * gp);
    a = fabsf(df);
}

// One LF step: u[] -> n[] (and u[] updated). Wave-local shfl halo exchange.
__device__ __forceinline__ void lf_step(float u[CPL], float n[CPL],
                                        int lane, bool bcL, bool bcR,
                                        float dtdx) {
    float f[CPL], a[CPL];
    #pragma unroll
    for (int j = 0; j < CPL; ++j) f_and_a(u[j], f[j], a[j]);

    float ul = __shfl_up(u[CPL - 1], 1);
    float fl = __shfl_up(f[CPL - 1], 1);
    float al = __shfl_up(a[CPL - 1], 1);
    float ur = __shfl_down(u[0], 1);
    float fr = __shfl_down(f[0], 1);
    float ar = __shfl_down(a[0], 1);
    if (lane == 0)  { ul = u[0];        fl = f[0];        al = a[0]; }
    if (lane == 63) { ur = u[CPL - 1];  fr = f[CPL - 1];  ar = a[CPL - 1]; }

    float fh[CPL + 1];
    fh[0] = 0.5f * (fl + f[0]) - 0.5f * fmaxf(al, a[0]) * (u[0] - ul);
    #pragma unroll
    for (int j = 1; j < CPL; ++j)
        fh[j] = 0.5f * (f[j - 1] + f[j]) - 0.5f * fmaxf(a[j - 1], a[j]) * (u[j] - u[j - 1]);
    fh[CPL] = 0.5f * (f[CPL - 1] + fr) - 0.5f * fmaxf(a[CPL - 1], ar) * (ur - u[CPL - 1]);

    #pragma unroll
    for (int j = 0; j < CPL; ++j) n[j] = u[j] - dtdx * (fh[j + 1] - fh[j]);

    // outflow BCs: u[0]=u[1], u[N-1]=u[N-2] (firewall against halo garbage)
    if (bcL) n[0] = n[1];
    if (bcR) n[CPL - 1] = n[CPL - 2];

    #pragma unroll
    for (int j = 0; j < CPL; ++j) u[j] = n[j];
}

__device__ __forceinline__ void store8(float* p, const float n[CPL]) {
    *(float4*)(p)     = make_float4(n[0], n[1], n[2], n[3]);
    *(float4*)(p + 4) = make_float4(n[4], n[5], n[6], n[7]);
}

__global__ __launch_bounds__(64) void lf_wave(const float* __restrict__ in_state,
                                              float* __restrict__ out,
                                              int s0, int nsteps) {
    const int lane  = threadIdx.x;          // one wave per block
    const int wid   = blockIdx.x;
    const int chunk = wid & (CHUNKS - 1);
    const int row   = wid >> 4;             // CHUNKS == 16
    const int gbase = chunk * OWN - HALO;
    const int c0    = lane * CPL;

    const float dtdx = (float)(0.0009 / (10.0 / 4096.0));

    float u[CPL];
    {
        const float* ip = in_state + (size_t)row * NCELL;
        #pragma unroll
        for (int j = 0; j < CPL; ++j) {
            int g = gbase + c0 + j;
            g = min(max(g, 0), NCELL - 1);
            u[j] = ip[g];
        }
    }

    // owned cells [HALO, HALO+OWN) = [128,384) -> lanes 16..47 (all 8 cells)
    const bool owned = (lane >= 16) && (lane < 48);
    const bool bcL = (chunk == 0) && (lane == 16);            // global cell 0
    const bool bcR = (chunk == CHUNKS - 1) && (lane == 47);   // global cell N-1

    float* op = out + (size_t)(s0 + 1) * BN + (size_t)row * NCELL + (gbase + c0);

    int t = 0;
    // groups of 4 steps, stores batched per group (R4 scheme, kept)
    for (; t + 4 <= nsteps; t += 4) {
        float b0[CPL], b1[CPL], b2[CPL], b3[CPL];
        lf_step(u, b0, lane, bcL, bcR, dtdx);
        lf_step(u, b1, lane, bcL, bcR, dtdx);
        lf_step(u, b2, lane, bcL, bcR, dtdx);
        lf_step(u, b3, lane, bcL, bcR, dtdx);
        if (owned) {
            store8(op,          b0);
            store8(op + BN,     b1);
            store8(op + 2 * BN, b2);
            store8(op + 3 * BN, b3);
        }
        op += 4 * BN;
    }
    // tail (not hit for nsteps=120, kept for robustness)
    for (; t < nsteps; ++t) {
        float n[CPL];
        lf_step(u, n, lane, bcL, bcR, dtdx);
        if (owned) store8(op, n);
        op += BN;
    }
}

extern "C" void kernel_launch(void* const* d_in, const int* in_sizes, int n_in,
                              void* d_out, int out_size, void* d_ws, size_t ws_size,
                              hipStream_t stream) {
    const float* init = (const float*)d_in[0];
    float* out = (float*)d_out;

    const int total = out_size / BN - 1;

    // plane 0 = init
    hipMemcpyAsync(d_out, init, (size_t)BN * sizeof(float),
                   hipMemcpyDeviceToDevice, stream);

    const int nblocks = CHUNKS * BATCHN;    // 512 waves
    for (int s = 0; s < total; s += KSTEP) {
        int ns = (total - s) < KSTEP ? (total - s) : KSTEP;
        lf_wave<<<nblocks, 64, 0, stream>>>(out + (size_t)s * BN, out, s, ns);
    }
}

// Round 6
// 255.686 us; speedup vs baseline: 1.3646x; 1.3646x over previous
//
#include <hip/hip_runtime.h>

// Problem constants (match reference)
#define BATCHN 32
#define NCELL  4096
#define BN     (BATCHN * NCELL)

// Round 6: R4 geometry, restructured halo exchange.
// R1-R5 post-mortems: per-step cost ~900 cyc (CPL=4) scaling with per-lane
// work; launches/barriers/store-drains all falsified as limiters. Theory:
// 6 shfl+clamp pairs serialize (~6 x 100 cyc DS latency) because each shfl
// result had an immediate dependent cndmask. Fix:
//   - exchange ONLY u (2 ds_bpermute, precomputed clamped byte addrs,
//     no post-clamp) issued FIRST in the step;
//   - recompute neighbor f,|f'| locally from exchanged u (identical f32
//     sequence -> owned cells bit-identical);
//   - bpermute latency hides under the 4 own f_and_a evals.
constexpr int OWN    = 128;
constexpr int HALO   = 64;
constexpr int CPL    = 4;                  // cells per lane
constexpr int CELLS  = 64 * CPL;           // 256 = OWN + 2*HALO
constexpr int KSTEP  = 60;                 // steps per launch (< HALO)
constexpr int CHUNKS = NCELL / OWN;        // 32

// f(u) and |f'(u)| exactly as the reference's f_real + jvp derivative.
__device__ __forceinline__ void f_and_a(float u, float& f, float& a) {
    const float C56 = 0.8333333333333333f;  // 10/12 rounded to f32
    float u2 = u * u;
    float u4 = u2 * u2;
    float g  = 0.75f - 2.0f * u + 1.5f * u2 - 0.25f * u4;
    f = 0.5f * u * (3.0f - u2) + C56 * (u2 * g);
    float gp = -2.0f + 3.0f * u - u2 * u;
    float df = (1.5f - 1.5f * u2) + C56 * (2.0f * u * g + u2 * gp);
    a = fabsf(df);
}

__device__ __forceinline__ float bperm(int addr4, float v) {
    return __int_as_float(__builtin_amdgcn_ds_bpermute(addr4, __float_as_int(v)));
}

// One LF step. aL/aR: precomputed clamped neighbor-lane byte addresses.
__device__ __forceinline__ void lf_step(float u[CPL], float n[CPL],
                                        int aL, int aR, bool bcL, bool bcR,
                                        float dtdx) {
    // 1) exchange u edges first — 2 DS ops in flight under the evals below
    float ul = bperm(aL, u[CPL - 1]);
    float ur = bperm(aR, u[0]);

    // 2) own-cell evals (~200 cyc of independent VALU: hides DS latency)
    float f[CPL], a[CPL];
    #pragma unroll
    for (int j = 0; j < CPL; ++j) f_and_a(u[j], f[j], a[j]);

    // 3) neighbor evals from exchanged u (identical sequence -> identical f32)
    float fl, al, fr, ar;
    f_and_a(ul, fl, al);
    f_and_a(ur, fr, ar);

    // 4) fluxes + update
    float fh[CPL + 1];
    fh[0] = 0.5f * (fl + f[0]) - 0.5f * fmaxf(al, a[0]) * (u[0] - ul);
    #pragma unroll
    for (int j = 1; j < CPL; ++j)
        fh[j] = 0.5f * (f[j - 1] + f[j]) - 0.5f * fmaxf(a[j - 1], a[j]) * (u[j] - u[j - 1]);
    fh[CPL] = 0.5f * (f[CPL - 1] + fr) - 0.5f * fmaxf(a[CPL - 1], ar) * (ur - u[CPL - 1]);

    #pragma unroll
    for (int j = 0; j < CPL; ++j) n[j] = u[j] - dtdx * (fh[j + 1] - fh[j]);

    // outflow BCs: u[0]=u[1], u[N-1]=u[N-2] (firewall against halo garbage)
    if (bcL) n[0] = n[1];
    if (bcR) n[CPL - 1] = n[CPL - 2];

    #pragma unroll
    for (int j = 0; j < CPL; ++j) u[j] = n[j];
}

__global__ __launch_bounds__(64) void lf_wave(const float* __restrict__ in_state,
                                              float* __restrict__ out,
                                              int s0, int nsteps) {
    const int lane  = threadIdx.x;          // one wave per block
    const int wid   = blockIdx.x;
    const int chunk = wid & (CHUNKS - 1);
    const int row   = wid >> 5;             // CHUNKS == 32
    const int gbase = chunk * OWN - HALO;
    const int c0    = lane * CPL;

    const float dtdx = (float)(0.0009 / (10.0 / 4096.0));

    // clamped neighbor-lane byte addresses for ds_bpermute (loop-invariant).
    // Edge lanes read their own value — affects halo evolution only; the
    // 60-step contamination cone never reaches owned cells [64,192).
    const int aL = max(lane - 1, 0) * 4;
    const int aR = min(lane + 1, 63) * 4;

    float u[CPL];
    {
        const float* ip = in_state + (size_t)row * NCELL;
        #pragma unroll
        for (int j = 0; j < CPL; ++j) {
            int g = gbase + c0 + j;
            g = min(max(g, 0), NCELL - 1);
            u[j] = ip[g];
        }
    }

    // owned cells [64,192) -> lanes 16..47 (all 4 cells contiguous)
    const bool owned = (lane >= 16) && (lane < 48);
    const bool bcL = (chunk == 0) && (lane == 16);            // global cell 0
    const bool bcR = (chunk == CHUNKS - 1) && (lane == 47);   // global cell N-1

    float* op = out + (size_t)(s0 + 1) * BN + (size_t)row * NCELL + (gbase + c0);

    int t = 0;
    // groups of 4 steps, stores batched per group (R4 scheme, kept)
    for (; t + 4 <= nsteps; t += 4) {
        float b0[CPL], b1[CPL], b2[CPL], b3[CPL];
        lf_step(u, b0, aL, aR, bcL, bcR, dtdx);
        lf_step(u, b1, aL, aR, bcL, bcR, dtdx);
        lf_step(u, b2, aL, aR, bcL, bcR, dtdx);
        lf_step(u, b3, aL, aR, bcL, bcR, dtdx);
        if (owned) {
            *(float4*)(op)            = make_float4(b0[0], b0[1], b0[2], b0[3]);
            *(float4*)(op + BN)       = make_float4(b1[0], b1[1], b1[2], b1[3]);
            *(float4*)(op + 2 * BN)   = make_float4(b2[0], b2[1], b2[2], b2[3]);
            *(float4*)(op + 3 * BN)   = make_float4(b3[0], b3[1], b3[2], b3[3]);
        }
        op += 4 * BN;
    }
    // tail (not hit for nsteps=60, kept for robustness)
    for (; t < nsteps; ++t) {
        float n[CPL];
        lf_step(u, n, aL, aR, bcL, bcR, dtdx);
        if (owned) *(float4*)op = make_float4(n[0], n[1], n[2], n[3]);
        op += BN;
    }
}

extern "C" void kernel_launch(void* const* d_in, const int* in_sizes, int n_in,
                              void* d_out, int out_size, void* d_ws, size_t ws_size,
                              hipStream_t stream) {
    const float* init = (const float*)d_in[0];
    float* out = (float*)d_out;

    const int total = out_size / BN - 1;

    // plane 0 = init
    hipMemcpyAsync(d_out, init, (size_t)BN * sizeof(float),
                   hipMemcpyDeviceToDevice, stream);

    const int nblocks = CHUNKS * BATCHN;    // 1024 waves
    for (int s = 0; s < total; s += KSTEP) {
        int ns = (total - s) < KSTEP ? (total - s) : KSTEP;
        lf_wave<<<nblocks, 64, 0, stream>>>(out + (size_t)s * BN, out, s, ns);
    }
}

// Round 7
// 163.760 us; speedup vs baseline: 2.1306x; 1.5613x over previous
//
#include <hip/hip_runtime.h>

// Problem constants (match reference)
#define BATCHN 32
#define NCELL  4096
#define BN     (BATCHN * NCELL)

// Round 7: R4 structure, VALU-issue-minimized step.
// Model from R1-R6: dur = ~180 us harness poison-fill (1.26 GB @ 87% HBM peak,
// visible as top dispatch in every profile) + kernel (~55 us, at its VALU
// issue floor of ~220 cyc/step at 1 wave/SIMD). This round cuts issue:
//  - f,|f'| expanded to monomial form with 0.5 PRE-FOLDED:
//      hf = 0.5 f  = 0.75u +0.3125u^2 -13/12 u^3 +0.625u^4 -5/48 u^6
//      ha = 0.5|f'| = |0.75 +0.625u -3.25u^2 +2.5u^3 -0.625u^5|
//    flux: fh = (hf_l+hf_r) - max(ha_l,ha_r)*(u_r-u_l)   (exact refold:
//    0.5*max(a,b) == max(0.5a,0.5b))
//  - cell pairs evaluated as ext_vector float2 -> v_pk_fma_f32 (packed f32)
//  - pairs packed (u0,u3),(u1,u2): edge pair done first so the 6 bpermutes
//    issue early; (u1,u2) eval + fluxes hide the ~100cyc DS latency.
constexpr int OWN    = 128;
constexpr int HALO   = 64;
constexpr int CPL    = 4;                  // cells per lane
constexpr int KSTEP  = 60;                 // steps per launch (< HALO)
constexpr int CHUNKS = NCELL / OWN;        // 32

typedef float v2f __attribute__((ext_vector_type(2)));

// hf = 0.5*f_real(u), ha = 0.5*|f_real'(u)| — coefficients verified vs
// reference at u=1 (f=1, f'=0) and u=0.5 (f=0.710286, f'=1.085938).
__device__ __forceinline__ void eval2(v2f u, v2f& hf, v2f& ha) {
    v2f u2 = u * u;
    v2f u3 = u2 * u;
    v2f p1 = u * 0.3125f + 0.75f;
    v2f A  = u * p1;                               // 0.75u + 0.3125u^2
    v2f p2 = u * 0.625f + (-1.0833333333333333f);  // -13/12 + 0.625u
    v2f B  = u3 * p2 + A;
    v2f u6 = u3 * u3;
    hf = u6 * (-0.10416666666666667f) + B;         // -5/48 u^6
    v2f p3 = u * 0.625f + 0.75f;
    v2f p4 = u * 2.5f + (-3.25f);
    v2f C  = u2 * p4 + p3;                         // 0.75+0.625u-3.25u^2+2.5u^3
    v2f u5 = u2 * u3;
    v2f hd = u5 * (-0.625f) + C;
    ha.x = fabsf(hd.x);
    ha.y = fabsf(hd.y);
}

__device__ __forceinline__ float bperm(int addr4, float v) {
    return __int_as_float(__builtin_amdgcn_ds_bpermute(addr4, __float_as_int(v)));
}

// One LF step on 4 cells/lane held as P=(u0,u3), Q=(u1,u2).
__device__ __forceinline__ void lf_step(v2f& P, v2f& Q, float n[CPL],
                                        int aL, int aR, bool bcL, bool bcR,
                                        float dtdx) {
    // edge pair first -> bpermutes issue as early as possible
    v2f hfP, haP;
    eval2(P, hfP, haP);
    float ul  = bperm(aL, P.y);    // left neighbor's cell 3
    float hfl = bperm(aL, hfP.y);
    float hal = bperm(aL, haP.y);
    float ur  = bperm(aR, P.x);    // right neighbor's cell 0
    float hfr = bperm(aR, hfP.x);
    float har = bperm(aR, haP.x);

    // inner pair eval overlaps the DS latency
    v2f hfQ, haQ;
    eval2(Q, hfQ, haQ);

    // 5 interface fluxes (0.5 pre-folded into hf/ha)
    float fh0 = (hfl   + hfP.x) - fmaxf(hal,   haP.x) * (P.x - ul);
    float fh1 = (hfP.x + hfQ.x) - fmaxf(haP.x, haQ.x) * (Q.x - P.x);
    float fh2 = (hfQ.x + hfQ.y) - fmaxf(haQ.x, haQ.y) * (Q.y - Q.x);
    float fh3 = (hfQ.y + hfP.y) - fmaxf(haQ.y, haP.y) * (P.y - Q.y);
    float fh4 = (hfP.y + hfr  ) - fmaxf(haP.y, har  ) * (ur  - P.y);

    n[0] = P.x - dtdx * (fh1 - fh0);
    n[1] = Q.x - dtdx * (fh2 - fh1);
    n[2] = Q.y - dtdx * (fh3 - fh2);
    n[3] = P.y - dtdx * (fh4 - fh3);

    // outflow BCs: u[0]=u[1], u[N-1]=u[N-2] (firewall against halo garbage)
    if (bcL) n[0] = n[1];
    if (bcR) n[3] = n[2];

    P.x = n[0]; P.y = n[3];
    Q.x = n[1]; Q.y = n[2];
}

__global__ __launch_bounds__(64) void lf_wave(const float* __restrict__ in_state,
                                              float* __restrict__ out,
                                              int s0, int nsteps) {
    const int lane  = threadIdx.x;          // one wave per block
    const int wid   = blockIdx.x;
    const int chunk = wid & (CHUNKS - 1);
    const int row   = wid >> 5;             // CHUNKS == 32
    const int gbase = chunk * OWN - HALO;
    const int c0    = lane * CPL;

    const float dtdx = (float)(0.0009 / (10.0 / 4096.0));

    // clamped neighbor-lane byte addresses (edge lanes read self; the
    // 60-step contamination cone never reaches owned cells [64,192))
    const int aL = max(lane - 1, 0) * 4;
    const int aR = min(lane + 1, 63) * 4;

    float uin[CPL];
    {
        const float* ip = in_state + (size_t)row * NCELL;
        #pragma unroll
        for (int j = 0; j < CPL; ++j) {
            int g = gbase + c0 + j;
            g = min(max(g, 0), NCELL - 1);
            uin[j] = ip[g];
        }
    }
    v2f P, Q;
    P.x = uin[0]; P.y = uin[3];
    Q.x = uin[1]; Q.y = uin[2];

    // owned cells [64,192) -> lanes 16..47 (all 4 cells contiguous)
    const bool owned = (lane >= 16) && (lane < 48);
    const bool bcL = (chunk == 0) && (lane == 16);            // global cell 0
    const bool bcR = (chunk == CHUNKS - 1) && (lane == 47);   // global cell N-1

    float* op = out + (size_t)(s0 + 1) * BN + (size_t)row * NCELL + (gbase + c0);

    int t = 0;
    // groups of 4 steps, stores batched per group (R4 scheme, kept)
    for (; t + 4 <= nsteps; t += 4) {
        float b0[CPL], b1[CPL], b2[CPL], b3[CPL];
        lf_step(P, Q, b0, aL, aR, bcL, bcR, dtdx);
        lf_step(P, Q, b1, aL, aR, bcL, bcR, dtdx);
        lf_step(P, Q, b2, aL, aR, bcL, bcR, dtdx);
        lf_step(P, Q, b3, aL, aR, bcL, bcR, dtdx);
        if (owned) {
            *(float4*)(op)            = make_float4(b0[0], b0[1], b0[2], b0[3]);
            *(float4*)(op + BN)       = make_float4(b1[0], b1[1], b1[2], b1[3]);
            *(float4*)(op + 2 * BN)   = make_float4(b2[0], b2[1], b2[2], b2[3]);
            *(float4*)(op + 3 * BN)   = make_float4(b3[0], b3[1], b3[2], b3[3]);
        }
        op += 4 * BN;
    }
    // tail (not hit for nsteps=60, kept for robustness)
    for (; t < nsteps; ++t) {
        float n[CPL];
        lf_step(P, Q, n, aL, aR, bcL, bcR, dtdx);
        if (owned) *(float4*)op = make_float4(n[0], n[1], n[2], n[3]);
        op += BN;
    }
}

extern "C" void kernel_launch(void* const* d_in, const int* in_sizes, int n_in,
                              void* d_out, int out_size, void* d_ws, size_t ws_size,
                              hipStream_t stream) {
    const float* init = (const float*)d_in[0];
    float* out = (float*)d_out;

    const int total = out_size / BN - 1;

    // plane 0 = init
    hipMemcpyAsync(d_out, init, (size_t)BN * sizeof(float),
                   hipMemcpyDeviceToDevice, stream);

    const int nblocks = CHUNKS * BATCHN;    // 1024 waves, 1/SIMD chip-wide
    for (int s = 0; s < total; s += KSTEP) {
        int ns = (total - s) < KSTEP ? (total - s) : KSTEP;
        lf_wave<<<nblocks, 64, 0, stream>>>(out + (size_t)s * BN, out, s, ns);
    }
}